// Round 4
// baseline (30.817 us; speedup 1.0000x reference)
//
#include <hip/hip_runtime.h>
#include <hip/hip_bf16.h>

#define NODE_V 16
#define EDGE_V 8
#define BATCH  64
#define NSEQ   256

#define EDGE_ELEMS  (BATCH * NSEQ * NSEQ)   // 4,194,304
#define EPB         2048                    // edge elems per block
#define EDGE_BLOCKS (EDGE_ELEMS / EPB)      // 2048
#define BLKS_PER_B  (NSEQ * NSEQ / EPB)     // 32 blocks per batch
#define NODE_OUT_FLOATS ((size_t)BATCH * NSEQ * NODE_V)  // 262,144

typedef float f32x4 __attribute__((ext_vector_type(4)));  // clang vector: OK for nontemporal builtins

// ---------------------------------------------------------------------------
// Fused, write-bound kernel.
//  - Blocks [0, 2048): edges (2048 elems each). Blocks [2048, 2112): nodes.
//  - Lane owns an OUTPUT float4 slot -> every global_store_dwordx4 is a fully
//    contiguous 1 KB/wave write (nontemporal: streaming, early L2 evict).
//  - Source element re-derived as q>>1 (edges) / q>>2 (nodes); adjacent lanes
//    share the load cache line.
//  - Per-batch logprob tables (9x8 / 17x16 distinct values) built in LDS by
//    parallel threads + shuffle reductions: no per-element transcendentals,
//    minimal pre-store latency.
// ---------------------------------------------------------------------------
__global__ __launch_bounds__(256) void fused_kernel(const float* __restrict__ xn,
                                                    const float* __restrict__ xe,
                                                    const float* __restrict__ g0,
                                                    float* __restrict__ out) {
    const int tid = threadIdx.x;
    if (blockIdx.x < EDGE_BLOCKS) {
        // ------------------------- edges -------------------------
        __shared__ __align__(16) float tbl[9 * 12];   // row stride 12 floats
        const int blk = blockIdx.x;
        const int b   = blk / BLKS_PER_B;

        if (tid < 72) {                                // 9 buckets x 8 vals
            const float inv = expf(-0.5f * g0[b]);
            const int bucket = tid >> 3;
            const int v      = tid & 7;
            const float z  = 2.0f * ((float)bucket + 0.5f) / (float)EDGE_V - 1.0f;
            const float ev = 2.0f * ((float)v + 0.5f) / (float)EDGE_V - 1.0f;
            const float d  = (z - ev) * inv;
            const float l  = -0.5f * d * d;
            float m = l;
            #pragma unroll
            for (int off = 1; off < 8; off <<= 1) m = fmaxf(m, __shfl_xor(m, off, 8));
            float s = expf(l - m);
            #pragma unroll
            for (int off = 1; off < 8; off <<= 1) s += __shfl_xor(s, off, 8);
            tbl[bucket * 12 + v] = l - m - logf(s);
        }
        __syncthreads();

        const f32x4* t4 = (const f32x4*)tbl;
        f32x4* o4 = (f32x4*)(out + NODE_OUT_FLOATS);
        const size_t qbase = (size_t)blk * (EPB * 2);  // float4 slots
        #pragma unroll
        for (int r = 0; r < EPB * 2 / 256; ++r) {      // 16 iters
            const size_t q = qbase + (size_t)(r * 256 + tid);
            const float x = xe[q >> 1];
            const int bucket = (int)rintf(x);          // 0..8, half-to-even
            const f32x4 val = t4[bucket * 3 + (int)(q & 1)];
            __builtin_nontemporal_store(val, &o4[q]);
        }
    } else {
        // ------------------------- nodes -------------------------
        __shared__ __align__(16) float tbl[17 * 20];   // row stride 20 floats
        const int b = blockIdx.x - EDGE_BLOCKS;

        const float inv = expf(-0.5f * g0[b]);
        #pragma unroll
        for (int pass = 0; pass < 2; ++pass) {         // 272 entries, 256 threads
            const int e = pass * 256 + tid;
            if (e < 17 * 16) {
                const int bucket = e >> 4;
                const int v      = e & 15;
                const float z  = 2.0f * ((float)bucket + 0.5f) / (float)NODE_V - 1.0f;
                const float ev = 2.0f * ((float)v + 0.5f) / (float)NODE_V - 1.0f;
                const float d  = (z - ev) * inv;
                const float l  = -0.5f * d * d;
                float m = l;
                #pragma unroll
                for (int off = 1; off < 16; off <<= 1) m = fmaxf(m, __shfl_xor(m, off, 16));
                float s = expf(l - m);
                #pragma unroll
                for (int off = 1; off < 16; off <<= 1) s += __shfl_xor(s, off, 16);
                tbl[bucket * 20 + v] = l - m - logf(s);
            }
        }
        __syncthreads();

        const f32x4* t4 = (const f32x4*)tbl;
        f32x4* o4 = (f32x4*)out;
        const size_t qbase = (size_t)b * 1024;         // 256 elems * 4 float4
        #pragma unroll
        for (int r = 0; r < 4; ++r) {
            const int q = r * 256 + tid;
            const float x = xn[b * NSEQ + (q >> 2)];
            const int bucket = (int)rintf(x);          // 0..16
            const f32x4 val = t4[bucket * 5 + (q & 3)];
            __builtin_nontemporal_store(val, &o4[qbase + q]);
        }
    }
}

extern "C" void kernel_launch(void* const* d_in, const int* in_sizes, int n_in,
                              void* d_out, int out_size, void* d_ws, size_t ws_size,
                              hipStream_t stream) {
    const float* xn = (const float*)d_in[0];   // [64, 256, 1]
    const float* xe = (const float*)d_in[1];   // [64, 256, 256]
    const float* g0 = (const float*)d_in[2];   // [64]
    float* out = (float*)d_out;

    fused_kernel<<<dim3(EDGE_BLOCKS + BATCH), dim3(256), 0, stream>>>(xn, xe, g0, out);
}

// Round 5
// 27.794 us; speedup vs baseline: 1.1088x; 1.1088x over previous
//
#include <hip/hip_runtime.h>
#include <hip/hip_bf16.h>

#define NODE_V 16
#define EDGE_V 8
#define BATCH  64
#define NSEQ   256

#define EDGE_ELEMS  (BATCH * NSEQ * NSEQ)   // 4,194,304
#define EPB         2048                    // edge elems per block
#define EDGE_BLOCKS (EDGE_ELEMS / EPB)      // 2048
#define BLKS_PER_B  (NSEQ * NSEQ / EPB)     // 32 blocks per batch
#define NODE_OUT_FLOATS ((size_t)BATCH * NSEQ * NODE_V)  // 262,144

typedef float f32x4 __attribute__((ext_vector_type(4)));

// ---------------------------------------------------------------------------
// Fused, write-bound kernel.
//  - Blocks [0, 2048): edges (2048 elems each). Blocks [2048, 2112): nodes.
//  - Lane owns an OUTPUT float4 slot -> every global_store_dwordx4 is a fully
//    contiguous 1 KB/wave write (REGULAR stores: let L2/L3 absorb the stream;
//    nt stores regressed 28.7->30.8 in R3/R4).
//  - Source element re-derived as q>>1 (edges) / q>>2 (nodes); adjacent lanes
//    share the load cache line (L1-served duplicate).
//  - Per-batch logprob tables (9x8 / 17x16 distinct values) built in LDS by
//    parallel threads + shuffle reductions: no per-element transcendentals.
// ---------------------------------------------------------------------------
__global__ __launch_bounds__(256) void fused_kernel(const float* __restrict__ xn,
                                                    const float* __restrict__ xe,
                                                    const float* __restrict__ g0,
                                                    float* __restrict__ out) {
    const int tid = threadIdx.x;
    if (blockIdx.x < EDGE_BLOCKS) {
        // ------------------------- edges -------------------------
        __shared__ __align__(16) float tbl[9 * 12];   // row stride 12 floats
        const int blk = blockIdx.x;
        const int b   = blk / BLKS_PER_B;

        if (tid < 72) {                                // 9 buckets x 8 vals
            const float inv = expf(-0.5f * g0[b]);
            const int bucket = tid >> 3;
            const int v      = tid & 7;
            const float z  = 2.0f * ((float)bucket + 0.5f) / (float)EDGE_V - 1.0f;
            const float ev = 2.0f * ((float)v + 0.5f) / (float)EDGE_V - 1.0f;
            const float d  = (z - ev) * inv;
            const float l  = -0.5f * d * d;
            float m = l;
            #pragma unroll
            for (int off = 1; off < 8; off <<= 1) m = fmaxf(m, __shfl_xor(m, off, 8));
            float s = expf(l - m);
            #pragma unroll
            for (int off = 1; off < 8; off <<= 1) s += __shfl_xor(s, off, 8);
            tbl[bucket * 12 + v] = l - m - logf(s);
        }
        __syncthreads();

        const f32x4* t4 = (const f32x4*)tbl;
        f32x4* o4 = (f32x4*)(out + NODE_OUT_FLOATS);
        const size_t qbase = (size_t)blk * (EPB * 2);  // float4 slots
        #pragma unroll
        for (int r = 0; r < EPB * 2 / 256; ++r) {      // 16 iters
            const size_t q = qbase + (size_t)(r * 256 + tid);
            const float x = xe[q >> 1];
            const int bucket = (int)rintf(x);          // 0..8, half-to-even
            o4[q] = t4[bucket * 3 + (int)(q & 1)];
        }
    } else {
        // ------------------------- nodes -------------------------
        __shared__ __align__(16) float tbl[17 * 20];   // row stride 20 floats
        const int b = blockIdx.x - EDGE_BLOCKS;

        const float inv = expf(-0.5f * g0[b]);
        #pragma unroll
        for (int pass = 0; pass < 2; ++pass) {         // 272 entries, 256 threads
            const int e = pass * 256 + tid;
            if (e < 17 * 16) {
                const int bucket = e >> 4;
                const int v      = e & 15;
                const float z  = 2.0f * ((float)bucket + 0.5f) / (float)NODE_V - 1.0f;
                const float ev = 2.0f * ((float)v + 0.5f) / (float)NODE_V - 1.0f;
                const float d  = (z - ev) * inv;
                const float l  = -0.5f * d * d;
                float m = l;
                #pragma unroll
                for (int off = 1; off < 16; off <<= 1) m = fmaxf(m, __shfl_xor(m, off, 16));
                float s = expf(l - m);
                #pragma unroll
                for (int off = 1; off < 16; off <<= 1) s += __shfl_xor(s, off, 16);
                tbl[bucket * 20 + v] = l - m - logf(s);
            }
        }
        __syncthreads();

        const f32x4* t4 = (const f32x4*)tbl;
        f32x4* o4 = (f32x4*)out;
        const size_t qbase = (size_t)b * 1024;         // 256 elems * 4 float4
        #pragma unroll
        for (int r = 0; r < 4; ++r) {
            const int q = r * 256 + tid;
            const float x = xn[b * NSEQ + (q >> 2)];
            const int bucket = (int)rintf(x);          // 0..16
            o4[qbase + q] = t4[bucket * 5 + (q & 3)];
        }
    }
}

extern "C" void kernel_launch(void* const* d_in, const int* in_sizes, int n_in,
                              void* d_out, int out_size, void* d_ws, size_t ws_size,
                              hipStream_t stream) {
    const float* xn = (const float*)d_in[0];   // [64, 256, 1]
    const float* xe = (const float*)d_in[1];   // [64, 256, 256]
    const float* g0 = (const float*)d_in[2];   // [64]
    float* out = (float*)d_out;

    fused_kernel<<<dim3(EDGE_BLOCKS + BATCH), dim3(256), 0, stream>>>(xn, xe, g0, out);
}